// Round 11
// baseline (1838.802 us; speedup 1.0000x reference)
//
#include <hip/hip_runtime.h>
#include <math.h>

// Archetipes RNN scan: T=256 sequential steps, M=16 modules, H=256, I=128.
// R19 = R18 (proven 1054 us) with detection taken to PER-WAVE, PER-4-COLUMN
// granularity; wave0 detect funnel + LDS fan-out deleted.
// R18 post-mortem: prediction matched (stage-stampede theory confirmed;
// FETCH even dropped 74->64 MB from better arrival-window merging).
// Structure insight: wave w's group-k load (packets w*64+lane + 1024k)
// depends on only 4 columns (4w+64k .. +3), not the 64-column group R18
// gated on. Change:
//  - Each wave polls its OWN 16 flags: lane l<16 reads column
//    4w + (l&3) + 64*(l>>2) of replica (h+w)&15 (one coalesced
//    instruction, 4 lines). __ballot forms the readiness mask; group k's
//    nibble (lanes 4k..4k+3) all-set -> issue that stage load NOW.
//    Uniform control flow (ballot is wave-uniform). Loads stay in flight
//    across further polling; validated at the end.
//  - Deletes s_gog + LDS fan-out hop + wave0 detect bottleneck; each
//    wave's wake-up is bounded by its own 4-column sources.
//  - Poll traffic: 256 blk x 16 waves x 4 lines ~ 16K line-req/round =
//    3% of R8's disaster level, ~4x R14's (latency-null per R17). Flags
//    remain a HINT: embedded-tag validation retry is ground truth.
// Kept byte-for-byte: replicated flag lines g_done (plain stores,
// distinct addresses; R11 rule), coalesced column publish via s_pub
// (R12), padded LDS HP=260 (R10, verified), dense staging (R9), weights
// register-resident (R3), conn-sparsity olist (R4), LDS out-buffer +
// single flush (R7), ONE barrier/step, epoch-monotone tags (replay-safe).

#define DT_C    0.042f
#define GAMMA_C 2.7f
#define EPS_C   4.7f

constexpr int M = 16, H = 256, I = 128, T = 256;
constexpr int HP = H + 4;     // padded LDS row stride (16B-aligned, 2-way banks)
constexpr int NROW = M * H;   // 4096 packets per slot
constexpr int NBLK = 256;
constexpr int NTHR = 1024;    // 16 waves
constexpr int NREPF = 16;     // flag replica arrays (1 KB each)

typedef float f32x4 __attribute__((ext_vector_type(4)));
typedef unsigned long long u64;
typedef unsigned int u32;

// Slot s (s=0..T) = hy after s steps. Packet = (tag<<32)|float_bits,
// tag = base + s + 1. Flat index p = h*16 + m.
__device__ __align__(64) u64 g_hy[(size_t)(T + 1) * NROW];   // 8.4 MB
__device__ __align__(64) u32 g_done[NREPF][NBLK];            // 16 x 1 KB
__device__ u32 g_epoch;

__global__ __launch_bounds__(NTHR) void rnn_persistent(
    const float* __restrict__ x,      // T*I
    const float* __restrict__ wm,     // M*M*H*H
    const float* __restrict__ conn,   // M*M
    const float* __restrict__ mask,   // M
    const float* __restrict__ W_in,   // M*H*I
    const float* __restrict__ W_rec,  // M*H*H
    const float* __restrict__ bias,   // M*H
    float* __restrict__ out)          // T*M*2*H state_seq, then T*M*H fb_seq
{
  const int h    = blockIdx.x;
  const int tid  = threadIdx.x;
  const int m    = tid >> 6;      // wave = module
  const int lane = tid & 63;

  __shared__ float hy_lds[2][M * HP];   // 2 x 16.25 KB, layout [m][h] padded
  __shared__ float outb_hz[T][M];       // 16 KB
  __shared__ float outb_fb[T][M];       // 16 KB
  __shared__ u64   s_pub[M];            // publish gather (tagged packets)
  __shared__ float s_c[M * M];
  __shared__ float s_scal[M];
  __shared__ int   s_olist[M][M];
  __shared__ float s_oc[M][M];
  __shared__ int   s_ocnt[M];
  __shared__ u32   s_base;

  if (tid == 0)
    s_base = __hip_atomic_load(&g_epoch, __ATOMIC_RELAXED, __HIP_MEMORY_SCOPE_AGENT);
  if (tid < M) s_pub[tid] = 0ull;
  if (tid < M * M) s_c[tid] = conn[tid];
  __syncthreads();

  // ---- publish slot 0 = zeros + flags ASAP (before heavy weight loads) ----
  const u32 base = s_base;
  if (tid < M) {
    const u64 pkt0 = ((u64)(base + 1u) << 32);   // hy = 0.0f, tag = base+1
    __hip_atomic_store(&g_hy[(size_t)h * M + tid], pkt0,
                       __ATOMIC_RELAXED, __HIP_MEMORY_SCOPE_AGENT);
  }
  if (tid < NREPF)
    __hip_atomic_store(&g_done[tid][h], base + 1u,
                       __ATOMIC_RELAXED, __HIP_MEMORY_SCOPE_AGENT);

  if (tid < M) {
    float s = 0.f; int cnt = 0;
    for (int o = 0; o < M; ++o) {
      float c = s_c[tid * M + o];
      s += c;
      if (c != 0.f) { s_olist[tid][cnt] = o; s_oc[tid][cnt] = c; ++cnt; }
    }
    for (int k = cnt; k < M; ++k) { s_olist[tid][k] = 0; s_oc[tid][k] = 0.f; }
    s_ocnt[tid] = cnt;
    s_scal[tid] = 1.0f / fmaxf(s, 1.0f);
  }
  __syncthreads();

  const int   rowg  = m * H + h;    // global row (bias/W_rec/W_in)
  const float maskm = mask[m];
  const float biasv = bias[rowg];
  const float scal  = s_scal[m];
  const int   ocnt  = s_ocnt[m];

  // ---- one-time: weights into registers (conn pre-applied) ----
  f32x4 wreg[M];
#pragma unroll
  for (int k = 0; k < M; ++k) {
    if (k < ocnt) {
      const int o = s_olist[m][k];
      const f32x4 wv = *reinterpret_cast<const f32x4*>(
          wm + ((size_t)(m * M + o) * H + h) * H + 4 * lane);
      wreg[k] = wv * s_oc[m][k];
    } else {
      wreg[k] = (f32x4)0.f;
    }
  }
  const f32x4  wrec = *reinterpret_cast<const f32x4*>(W_rec + (size_t)rowg * H + 4 * lane);
  const float2 win  = *reinterpret_cast<const float2*>(W_in + (size_t)rowg * I + 2 * lane);

  float hz = 0.f;
  // x[0] prefetch (per-lane slice; same for every wave)
  float2 xd = *reinterpret_cast<const float2*>(x + 2 * lane);

  const int  mcol = (tid & 15) * HP;   // staging LDS column base
  const int  hrow = tid >> 4;          // staging LDS row (0..63)
  // per-wave flag pointer: lane l watches column 4m + (l&3) + 64*((l>>2)&3)
  const u32* fpw = &g_done[(h + m) & (NREPF - 1)]
                          [4 * m + (lane & 3) + 64 * ((lane >> 2) & 3)];
  int buf = 0;

  for (int t = 0; t < T; ++t) {
    const u32 tgt = base + (u32)t + 1u;
    const u64* src = g_hy + (size_t)t * NROW + tid;
    u64 a0 = 0, a1 = 0, a2 = 0, a3 = 0;

    // ---- per-wave detect: poll own 16 flags, issue loads per-nibble ----
    {
      u32 pend = 0xFu;
      do {
        const u32 f = __hip_atomic_load(fpw, __ATOMIC_RELAXED,
                                        __HIP_MEMORY_SCOPE_AGENT);
        const u64 rdy = __ballot(f >= tgt);
        if ((pend & 1u) && ((rdy & 0xFull) == 0xFull)) {
          a0 = __hip_atomic_load(src, __ATOMIC_RELAXED, __HIP_MEMORY_SCOPE_AGENT);
          pend &= ~1u;
        }
        if ((pend & 2u) && (((rdy >> 4) & 0xFull) == 0xFull)) {
          a1 = __hip_atomic_load(src + 1024, __ATOMIC_RELAXED, __HIP_MEMORY_SCOPE_AGENT);
          pend &= ~2u;
        }
        if ((pend & 4u) && (((rdy >> 8) & 0xFull) == 0xFull)) {
          a2 = __hip_atomic_load(src + 2048, __ATOMIC_RELAXED, __HIP_MEMORY_SCOPE_AGENT);
          pend &= ~4u;
        }
        if ((pend & 8u) && (((rdy >> 12) & 0xFull) == 0xFull)) {
          a3 = __hip_atomic_load(src + 3072, __ATOMIC_RELAXED, __HIP_MEMORY_SCOPE_AGENT);
          pend &= ~8u;
        }
        if (pend) __builtin_amdgcn_s_sleep(1);
      } while (pend);
    }
    asm volatile("" ::: "memory");

    // ---- validate embedded tags (flags are a hint; rare retry) ----
    {
      while (!((((u32)(a0 >> 32)) >= tgt) & (((u32)(a1 >> 32)) >= tgt) &
               (((u32)(a2 >> 32)) >= tgt) & (((u32)(a3 >> 32)) >= tgt))) {
        __builtin_amdgcn_s_sleep(1);
        a0 = __hip_atomic_load(src,        __ATOMIC_RELAXED, __HIP_MEMORY_SCOPE_AGENT);
        a1 = __hip_atomic_load(src + 1024, __ATOMIC_RELAXED, __HIP_MEMORY_SCOPE_AGENT);
        a2 = __hip_atomic_load(src + 2048, __ATOMIC_RELAXED, __HIP_MEMORY_SCOPE_AGENT);
        a3 = __hip_atomic_load(src + 3072, __ATOMIC_RELAXED, __HIP_MEMORY_SCOPE_AGENT);
      }
      float* dst = &hy_lds[buf][0];
      // packet p = tid + 1024k: module = tid&15, column = hrow + 64k
      dst[mcol + hrow      ] = __uint_as_float((u32)a0);
      dst[mcol + hrow +  64] = __uint_as_float((u32)a1);
      dst[mcol + hrow + 128] = __uint_as_float((u32)a2);
      dst[mcol + hrow + 192] = __uint_as_float((u32)a3);
    }
    __syncthreads();   // ONLY barrier per step; prev publish ack drains here

    // input term (xd prefetched last iteration)
    float acc_o = win.x * (maskm * xd.x);
    acc_o = fmaf(win.y, maskm * xd.y, acc_o);
    // recurrent term
    {
      const f32x4 hp = *reinterpret_cast<const f32x4*>(&hy_lds[buf][m * HP + 4 * lane]);
      acc_o = fmaf(wrec.x, hp.x, acc_o);
      acc_o = fmaf(wrec.y, hp.y, acc_o);
      acc_o = fmaf(wrec.z, hp.z, acc_o);
      acc_o = fmaf(wrec.w, hp.w, acc_o);
    }
    // feedback: register weights x LDS hy fragments
    float acc_fb = 0.f;
#pragma unroll
    for (int k = 0; k < M; ++k) {
      if (k < ocnt) {
        const int o = s_olist[m][k];
        const f32x4 hp = *reinterpret_cast<const f32x4*>(&hy_lds[buf][o * HP + 4 * lane]);
        float po = wreg[k].x * hp.x;
        po = fmaf(wreg[k].y, hp.y, po);
        po = fmaf(wreg[k].z, hp.z, po);
        po = fmaf(wreg[k].w, hp.w, po);
        acc_fb += po;
      }
    }

    // wave-wide butterfly reduce
    for (int off = 32; off > 0; off >>= 1) {
      acc_fb += __shfl_xor(acc_fb, off);
      acc_o  += __shfl_xor(acc_o,  off);
    }

    if (lane == 0) {
      const float fb   = scal * acc_fb;
      const float hy_p = hy_lds[buf][m * HP + h];
      const float pre  = acc_o + biasv + fb;
      const float hz_n = hz + DT_C * (tanhf(pre) - GAMMA_C * hy_p - EPS_C * hz);
      const float hy_n = hy_p + DT_C * hz_n;
      hz = hz_n;
      // drop tagged packet in LDS; wave0 publishes the whole column
      const u64 pkt = ((u64)(tgt + 1u) << 32) | (u64)__float_as_uint(hy_n);
      __hip_atomic_store(&s_pub[m], pkt, __ATOMIC_RELAXED,
                         __HIP_MEMORY_SCOPE_WORKGROUP);
      // buffer hz/fb in LDS; flushed once after the loop
      outb_hz[t][m] = hz_n;
      outb_fb[t][m] = fb;
    }
    asm volatile("" ::: "memory");

    // ---- wave0: gather 16 packets, ONE coalesced store, then flags ----
    if (m == 0) {
      u64 p;
      for (;;) {
        p = __hip_atomic_load(&s_pub[lane & 15], __ATOMIC_RELAXED,
                              __HIP_MEMORY_SCOPE_WORKGROUP);
        if (__all(((u32)(p >> 32)) >= tgt + 1u)) break;
      }
      if (lane < M)
        __hip_atomic_store(&g_hy[(size_t)(t + 1) * NROW + (size_t)h * M + lane],
                           p, __ATOMIC_RELAXED, __HIP_MEMORY_SCOPE_AGENT);
      // replicated completion flags (hint; tags validated by consumers)
      if (lane < NREPF)
        __hip_atomic_store(&g_done[lane][h], tgt + 1u,
                           __ATOMIC_RELAXED, __HIP_MEMORY_SCOPE_AGENT);
    }

    if (t + 1 < T)
      xd = *reinterpret_cast<const float2*>(x + (size_t)(t + 1) * I + 2 * lane);
    buf ^= 1;
  }

  __syncthreads();   // outb_* visible; final publishes drained (vmcnt(0))

  // ---- one-time flush: hy from own g_hy slots, hz/fb from LDS ----
  const size_t fb_base = (size_t)T * M * 2 * H;
  for (int i = tid; i < T * M; i += NTHR) {
    const int t  = i >> 4;
    const int mm = i & 15;
    const u64 q = __hip_atomic_load(
        &g_hy[(size_t)(t + 1) * NROW + (size_t)h * M + mm],
        __ATOMIC_RELAXED, __HIP_MEMORY_SCOPE_AGENT);
    const float hyv = __uint_as_float((u32)q);
    const size_t so = (size_t)t * (M * 2 * H) + (size_t)mm * (2 * H);
    out[so + h]     = hyv;
    out[so + H + h] = outb_hz[t][mm];
    out[fb_base + (size_t)t * (M * H) + (size_t)mm * H + h] = outb_fb[t][mm];
  }

  // epoch bump for next launch/replay: strictly above every tag used here
  if (h == 0 && tid == 0)
    __hip_atomic_store(&g_epoch, base + (u32)(T + 2),
                       __ATOMIC_RELAXED, __HIP_MEMORY_SCOPE_AGENT);
}

extern "C" void kernel_launch(void* const* d_in, const int* in_sizes, int n_in,
                              void* d_out, int out_size, void* d_ws, size_t ws_size,
                              hipStream_t stream) {
  const float* x     = (const float*)d_in[0];
  const float* wm    = (const float*)d_in[1];
  const float* conn  = (const float*)d_in[2];
  const float* mask  = (const float*)d_in[3];
  const float* W_in  = (const float*)d_in[4];
  const float* W_rec = (const float*)d_in[5];
  const float* bias  = (const float*)d_in[6];

  rnn_persistent<<<NBLK, NTHR, 0, stream>>>(
      x, wm, conn, mask, W_in, W_rec, bias, (float*)d_out);
}